// Round 4
// baseline (290.690 us; speedup 1.0000x reference)
//
#include <hip/hip_runtime.h>

#define STEPS 30
#define HID 32
#define TPB 256
#define LDS_STRIDE (STEPS + 1)   // 31: odd stride -> conflict-free column access

// Pin into a scalar / vector register; opaque to the compiler so the value
// cannot be rematerialized (reloaded) inside the loop.
#define PIN_S(x) asm volatile("" : "+s"(x))
#define PIN_V(x) asm volatile("" : "+v"(x))

__global__ __launch_bounds__(TPB, 3) void hedge_kernel(
    const float* __restrict__ S,
    const float* __restrict__ W1,
    const float* __restrict__ b1,
    const float* __restrict__ W2,
    const float* __restrict__ b2,
    const float* __restrict__ a_init,
    float* __restrict__ out)
{
    __shared__ float tile[TPB * LDS_STRIDE];   // 256*31*4 = 31744 B
    const int tid = threadIdx.x;
    const long long base = (long long)blockIdx.x * (TPB * STEPS);

    // ---- Stage S tile (256 elems x 30 steps) coalesced into padded LDS ----
    const float2* __restrict__ S2 = (const float2*)(S + base);
    #pragma unroll
    for (int k = 0; k < (TPB * STEPS) / (2 * TPB); ++k) {   // 15 iters
        int g2 = tid + k * TPB;
        float2 v = S2[g2];
        int g = g2 * 2;
        int row = g / STEPS;
        int col = g - row * STEPS;
        tile[row * LDS_STRIDE + col]     = v.x;
        tile[row * LDS_STRIDE + col + 1] = v.y;
    }

    // ---- Weights: wa,we wave-uniform -> SGPRs (0 VGPR cost); wc,wb,w2 -> VGPRs ----
    // Uniform kernel-arg pointers + constant indices => compiler emits s_load;
    // readfirstlane + PIN_S guarantees SGPR residency across the loop.
    float wa[HID], we[HID];          // SGPR: 64 scalars
    float wc[HID], wb[HID], w2[HID]; // VGPR: 96 regs
    #pragma unroll
    for (int j = 0; j < HID; ++j) {
        wa[j] = __uint_as_float(__builtin_amdgcn_readfirstlane(__float_as_uint(W1[0 * HID + j])));
        we[j] = __uint_as_float(__builtin_amdgcn_readfirstlane(__float_as_uint(W1[2 * HID + j])));
        PIN_S(wa[j]); PIN_S(we[j]);
        wc[j] = W1[1 * HID + j];
        wb[j] = b1[j];
        w2[j] = W2[j];
        PIN_V(wc[j]); PIN_V(wb[j]); PIN_V(w2[j]);
    }
    const float bias2 = b2[0];
    float d = a_init[0];
    float h = 0.0f;
    __syncthreads();

    // ---- Recurrence: one thread = one element ----
    float* my = &tile[tid * LDS_STRIDE];
    #pragma unroll 2   // ~350 instr body: I-cache safe, overlaps adjacent steps
    for (int t = 0; t < STEPS; ++t) {
        const float s = my[t];   // off-chain LDS read (conflict-free, stride 31)
        float acc[8];
        #pragma unroll
        for (int g = 0; g < 8; ++g) acc[g] = 0.0f;
        acc[0] = bias2;
        #pragma unroll
        for (int j = 0; j < HID; ++j) {
            // Each VALU op reads at most ONE SGPR (wa/we); wc,wb,w2 are VGPRs.
            float tj = fmaf(we[j], h, wb[j]);   // v_fma sD, vH, vWB   (1 sgpr)
            tj = fmaf(wc[j], d, tj);            // all-vgpr
            tj = fmaf(wa[j], s, tj);            // 1 sgpr
            acc[j & 7] = fmaf(fmaxf(tj, 0.0f), w2[j], acc[j & 7]);
        }
        float s01 = acc[0] + acc[1], s23 = acc[2] + acc[3];
        float s45 = acc[4] + acc[5], s67 = acc[6] + acc[7];
        const float dn = (s01 + s23) + (s45 + s67);
        h = fmaf(0.2f, dn, 0.8f * h);
        d = dn;
        my[t] = dn;              // S[t] consumed; slot reused for output d_t
    }
    __syncthreads();

    // ---- Dump outputs coalesced (same flat layout as S) ----
    float2* __restrict__ O2 = (float2*)(out + base);
    #pragma unroll
    for (int k = 0; k < (TPB * STEPS) / (2 * TPB); ++k) {   // 15 iters
        int g2 = tid + k * TPB;
        int g = g2 * 2;
        int row = g / STEPS;
        int col = g - row * STEPS;
        float2 v;
        v.x = tile[row * LDS_STRIDE + col];
        v.y = tile[row * LDS_STRIDE + col + 1];
        O2[g2] = v;
    }
}

extern "C" void kernel_launch(void* const* d_in, const int* in_sizes, int n_in,
                              void* d_out, int out_size, void* d_ws, size_t ws_size,
                              hipStream_t stream) {
    const float* S      = (const float*)d_in[0];
    const float* W1     = (const float*)d_in[1];
    const float* b1     = (const float*)d_in[2];
    const float* W2     = (const float*)d_in[3];
    const float* b2     = (const float*)d_in[4];
    const float* a_init = (const float*)d_in[5];
    float* out = (float*)d_out;

    const int batch = in_sizes[0] / STEPS;    // 1048576
    const int grid  = batch / TPB;            // 4096
    hedge_kernel<<<grid, TPB, 0, stream>>>(S, W1, b1, W2, b2, a_init, out);
}